// Round 1
// baseline (727.350 us; speedup 1.0000x reference)
//
#include <hip/hip_runtime.h>

#define EPT 16  // edges per thread; N_EDGES (33,554,432) is divisible by 16

__global__ __launch_bounds__(256) void zero_out_kernel(float* __restrict__ out, int n) {
    int i = blockIdx.x * blockDim.x + threadIdx.x;
    int n4 = n >> 2;
    if (i < n4) {
        reinterpret_cast<float4*>(out)[i] = float4{0.f, 0.f, 0.f, 0.f};
    }
    // tail (n % 4) — handled by first few threads
    int tail_start = n4 << 2;
    int t = tail_start + i;
    if (i < (n - tail_start)) {
        out[t] = 0.f;
    }
}

__global__ __launch_bounds__(256) void seg_gather_sum_kernel(
    const float* __restrict__ x,
    const int*   __restrict__ ptrs,
    const int*   __restrict__ csr,
    float*       __restrict__ out,
    int n_edges)
{
    long long tid = (long long)blockIdx.x * blockDim.x + threadIdx.x;
    long long e0  = tid * EPT;
    if (e0 >= n_edges) return;

    int   cs[EPT];
    float v[EPT];

    if (e0 + EPT <= n_edges) {
        // Vector loads: 4x int4 for csr, 4x int4 for ptrs (64B-aligned since
        // e0 is a multiple of 16 ints).
        const int4* c4 = reinterpret_cast<const int4*>(csr + e0);
        const int4* p4 = reinterpret_cast<const int4*>(ptrs + e0);
        int ps[EPT];
        #pragma unroll
        for (int q = 0; q < EPT / 4; ++q) {
            int4 c = c4[q];
            int4 p = p4[q];
            cs[q * 4 + 0] = c.x; cs[q * 4 + 1] = c.y;
            cs[q * 4 + 2] = c.z; cs[q * 4 + 3] = c.w;
            ps[q * 4 + 0] = p.x; ps[q * 4 + 1] = p.y;
            ps[q * 4 + 2] = p.z; ps[q * 4 + 3] = p.w;
        }
        // Issue all 16 gathers up front (independent loads -> latency overlap).
        #pragma unroll
        for (int i = 0; i < EPT; ++i) v[i] = x[ps[i]];

        int   cur   = cs[0];
        float sum   = 0.f;
        bool  first = true;
        #pragma unroll
        for (int i = 0; i < EPT; ++i) {
            int seg = cs[i];
            if (seg != cur) {
                // Flush previous run. The chunk's FIRST segment may be shared
                // with the previous thread -> atomic. Interior segments are
                // exclusive (csr sorted) -> plain store onto zeroed output.
                if (first) { atomicAdd(out + cur, sum); first = false; }
                else       { out[cur] = sum; }
                cur = seg;
                sum = 0.f;
            }
            sum += v[i];
        }
        // Last segment may continue into the next thread's chunk -> atomic.
        atomicAdd(out + cur, sum);
    } else {
        // Scalar tail (unused for the fixed problem size, kept for safety).
        int   cur   = csr[e0];
        float sum   = 0.f;
        bool  first = true;
        for (long long e = e0; e < n_edges; ++e) {
            int seg = csr[e];
            if (seg != cur) {
                if (first) { atomicAdd(out + cur, sum); first = false; }
                else       { out[cur] = sum; }
                cur = seg;
                sum = 0.f;
            }
            sum += x[ptrs[e]];
        }
        atomicAdd(out + cur, sum);
    }
}

extern "C" void kernel_launch(void* const* d_in, const int* in_sizes, int n_in,
                              void* d_out, int out_size, void* d_ws, size_t ws_size,
                              hipStream_t stream) {
    const float* x    = (const float*)d_in[0];
    const int*   ptrs = (const int*)d_in[1];
    const int*   csr  = (const int*)d_in[2];
    float*       out  = (float*)d_out;

    const int n_edges = in_sizes[2];  // csr length

    // 1) Zero the output (harness poisons d_out; empty segments must be 0,
    //    and the scatter kernel's atomics/stores build on a zero base).
    {
        int n4 = out_size >> 2;
        int threads = 256;
        int blocks = (n4 + threads - 1) / threads;
        if (blocks < 1) blocks = 1;
        zero_out_kernel<<<blocks, threads, 0, stream>>>(out, out_size);
    }

    // 2) Fused gather + sorted-segment scatter-add.
    {
        long long n_threads = ((long long)n_edges + EPT - 1) / EPT;
        int threads = 256;
        long long blocks = (n_threads + threads - 1) / threads;
        seg_gather_sum_kernel<<<(int)blocks, threads, 0, stream>>>(
            x, ptrs, csr, out, n_edges);
    }
}